// Round 3
// baseline (111.921 us; speedup 1.0000x reference)
//
#include <hip/hip_runtime.h>
#include <hip/hip_bf16.h>

// GEMM view: Out[(b,d), c] = sum_k A[(b,d),k] * Bk[k,c]
//   row = b*32 + d   (M = 131072)
//   k   = i*32 + j   (K = 1024)  -> MFMA step s covers i=s, j=0..31
//   col = c          (N = 64)
// A[(b,d), i*32+j] = x[b,i,d] * y[b,j,d]  (generated in registers)
// Bk[i*32+j, c]    = kernel[c,i,j]        (pre-swizzled bf16, frag order)
//
// R3: kswz + x staged to LDS via global_load_lds (16B), double-buffered
// 4-step chunks; per-block chunk-order rotation (blockIdx&7) to spread
// the L2 hotspot on the shared 128KB kswz. Block = 4 b's x full C,
// wave = 2 b's (4 M-tiles) x half C (2 N-tiles). LDS 48KB, 3 blocks/CU.

typedef __attribute__((ext_vector_type(8))) short short8;
typedef __attribute__((ext_vector_type(4))) float f32x4;

__device__ __forceinline__ unsigned short f2bf_rne(float f) {
    union { float f; unsigned u; } w; w.f = f;
    return (unsigned short)((w.u + 0x7FFFu + ((w.u >> 16) & 1u)) >> 16);
}

// kswz frag index g = (s*4 + nt)*64 + lane  (8192 frags of 16B)
// kswz[g*8 + t] = bf16(kernel[c = nt*16 + (lane&15)][s][(lane>>4)*8 + t])
__global__ __launch_bounds__(256) void kswz_kernel(const float* __restrict__ kern,
                                                   short* __restrict__ kswz) {
    int idx  = blockIdx.x * 256 + threadIdx.x;  // 8192
    int lane = idx & 63;
    int nt   = (idx >> 6) & 3;
    int s    = idx >> 8;
    int c    = nt * 16 + (lane & 15);
    int jb   = (lane >> 4) * 8;
    const float* src = kern + c * 1024 + s * 32 + jb;
    short8 v;
#pragma unroll
    for (int t = 0; t < 8; ++t) v[t] = (short)f2bf_rne(src[t]);
    *(short8*)(kswz + (size_t)idx * 8) = v;
}

// async 16B global->LDS; lds base must be wave-uniform (HW adds lane*16)
__device__ __forceinline__ void gld_lds16(const void* g, void* l) {
    __builtin_amdgcn_global_load_lds(
        (const __attribute__((address_space(1))) unsigned int*)g,
        (__attribute__((address_space(3))) unsigned int*)l, 16, 0, 0);
}

__global__ __launch_bounds__(256, 3) void cin_main(const float* __restrict__ x,
                                                   const float* __restrict__ y,
                                                   const short* __restrict__ kswz,
                                                   float* __restrict__ out_mat,
                                                   float* __restrict__ out_fin) {
    __shared__ __align__(16) float xs[4 * 1024];     // 16 KB: x[b_blk..+4)[i][d]
    __shared__ __align__(16) short kb[2][8192];      // 2 x 16 KB: 4-step B chunks

    const int tid  = threadIdx.x;
    const int wave = tid >> 6;
    const int lane = tid & 63;
    const int quad = lane >> 4;
    const int n16  = lane & 15;
    const int b_blk = blockIdx.x * 4;
    const int bpair = wave >> 1;   // 0..1
    const int nth   = wave & 1;    // half of C

    // ---- DMA x slice (16 KB) ----
    {
        const float* xg = x + (size_t)b_blk * 1024;
#pragma unroll
        for (int r = 0; r < 4; ++r)
            gld_lds16(xg + (r * 256 + tid) * 4, &xs[r * 1024 + wave * 256]);
    }
    // ---- DMA first kswz chunk ----
    const int cq0 = blockIdx.x & 7;
#pragma unroll
    for (int r = 0; r < 4; ++r)
        gld_lds16(kswz + ((size_t)cq0 * 8192 + (r * 256 + tid) * 8),
                  &kb[0][r * 2048 + wave * 512]);

    const int b0 = b_blk + bpair * 2;

    // ---- y fragments: yv[mt][t] = y[b, j=quad*8+t, d] ----
    float yv[4][8];
#pragma unroll
    for (int mt = 0; mt < 4; ++mt) {
        const int b = b0 + (mt >> 1);
        const int d = n16 + 16 * (mt & 1);
        const float* yp = y + (size_t)b * 1024 + (quad * 8) * 32 + d;
#pragma unroll
        for (int t = 0; t < 8; ++t) yv[mt][t] = yp[t * 32];
    }

    f32x4 acc[4][2];
#pragma unroll
    for (int mt = 0; mt < 4; ++mt)
#pragma unroll
        for (int ntl = 0; ntl < 2; ++ntl) acc[mt][ntl] = (f32x4){0.f, 0.f, 0.f, 0.f};

    // per-lane LDS read bases
    const short* kbL[2] = { &kb[0][lane * 8], &kb[1][lane * 8] };
    int xoff[4];
#pragma unroll
    for (int mt = 0; mt < 4; ++mt)
        xoff[mt] = (bpair * 2 + (mt >> 1)) * 1024 + n16 + 16 * (mt & 1);

    __syncthreads();

    for (int p = 0; p < 8; ++p) {
        if (p < 7) {  // DMA next chunk into other buffer
            const int cn = (cq0 + p + 1) & 7;
            short* dst = (short*)&kb[(p + 1) & 1][0];
#pragma unroll
            for (int r = 0; r < 4; ++r)
                gld_lds16(kswz + ((size_t)cn * 8192 + (r * 256 + tid) * 8),
                          dst + r * 2048 + wave * 512);
        }

        const short* kbase = kbL[p & 1];
        const int sbase = ((cq0 + p) & 7) * 4;
#pragma unroll
        for (int k = 0; k < 4; ++k) {
            const short8 bf0 = *(const short8*)(kbase + (k * 4 + nth * 2) * 512);
            const short8 bf1 = *(const short8*)(kbase + (k * 4 + nth * 2 + 1) * 512);
#pragma unroll
            for (int mt = 0; mt < 4; ++mt) {
                const float xv = xs[xoff[mt] + (sbase + k) * 32];
                union { short8 s8; __hip_bfloat162 h2[4]; } af;
#pragma unroll
                for (int pp = 0; pp < 4; ++pp) {
                    float2 pr = make_float2(xv * yv[mt][2 * pp], xv * yv[mt][2 * pp + 1]);
                    af.h2[pp] = __float22bfloat162_rn(pr);
                }
                acc[mt][0] = __builtin_amdgcn_mfma_f32_16x16x32_bf16(af.s8, bf0, acc[mt][0], 0, 0, 0);
                acc[mt][1] = __builtin_amdgcn_mfma_f32_16x16x32_bf16(af.s8, bf1, acc[mt][1], 0, 0, 0);
            }
        }
        __syncthreads();
    }

    // ---- epilogue: output_mat[b][c][d], d = 16*(mt&1) + quad*4 + t ----
#pragma unroll
    for (int mt = 0; mt < 4; ++mt) {
        const int b = b0 + (mt >> 1);
        const int dbase = 16 * (mt & 1) + quad * 4;
#pragma unroll
        for (int ntl = 0; ntl < 2; ++ntl) {
            const int c = (nth * 2 + ntl) * 16 + n16;
            *(f32x4*)(out_mat + (size_t)b * 2048 + c * 32 + dbase) = acc[mt][ntl];
        }
    }

    // ---- final_output[b][c] = sum_d output_mat[b][c][d] ----
#pragma unroll
    for (int a = 0; a < 2; ++a) {
        const int b = b0 + a;
#pragma unroll
        for (int ntl = 0; ntl < 2; ++ntl) {
            float f = 0.f;
#pragma unroll
            for (int t = 0; t < 4; ++t) f += acc[2 * a][ntl][t] + acc[2 * a + 1][ntl][t];
            f += __shfl_xor(f, 16);
            f += __shfl_xor(f, 32);
            if (lane < 16) out_fin[(size_t)b * 64 + (nth * 2 + ntl) * 16 + n16] = f;
        }
    }
}

extern "C" void kernel_launch(void* const* d_in, const int* in_sizes, int n_in,
                              void* d_out, int out_size, void* d_ws, size_t ws_size,
                              hipStream_t stream) {
    const float* x    = (const float*)d_in[0];   // [4096,32,32]
    const float* y    = (const float*)d_in[1];   // [4096,32,32]
    const float* kern = (const float*)d_in[2];   // [64,32,32]
    float* out_mat = (float*)d_out;                      // [4096,64,32]
    float* out_fin = (float*)d_out + 4096 * 64 * 32;     // [4096,64]
    short* kswz = (short*)d_ws;                          // 65536 bf16 = 128 KB

    kswz_kernel<<<32, 256, 0, stream>>>(kern, kswz);
    cin_main<<<1024, 256, 0, stream>>>(x, y, kswz, out_mat, out_fin);
}

// Round 5
// 100.788 us; speedup vs baseline: 1.1105x; 1.1105x over previous
//
#include <hip/hip_runtime.h>
#include <hip/hip_fp16.h>

// GEMM view: Out[(b,d), c] = sum_k A[(b,d),k] * Bk[k,c]
//   row = b*32 + d (M=131072), k = i*32+j (K=1024), col = c (N=64)
// A[(b,d), i*32+j] = x[b,i,d] * y[b,j,d]  — rank-1 in (i,j), built in regs.
// R5 (= R4 fixed): full-f16 datapath. x staged in LDS as dup'd f16 pairs
// (1 cvt_pkrtz at stage time), y as packed __fp16x2 in regs -> A-frag =
// 4 v_pk_mul_f16 + 1 ds_read_b32, zero in-loop converts. Wave = 2 b x
// FULL C. 512 blocks x 256 thr, 8 b/block, 64 KB LDS, 2 blocks/CU.

typedef __attribute__((ext_vector_type(8))) _Float16 half8;   // MFMA operand
typedef __attribute__((ext_vector_type(2))) __fp16 fp16x2;    // cvt_pkrtz/pk_mul
typedef __attribute__((ext_vector_type(4))) float f32x4;
typedef __attribute__((ext_vector_type(8))) short short8;

__device__ __forceinline__ unsigned int dup_h(float f) {
    union { fp16x2 h; unsigned int u; } w;
    w.h = __builtin_amdgcn_cvt_pkrtz(f, f);
    return w.u;
}
__device__ __forceinline__ fp16x2 pk2(float a, float b) {
    return __builtin_amdgcn_cvt_pkrtz(a, b);
}

// kswz f16 frag order: g = (s*4+nt)*64 + lane,
// kswz[g*8+t] = f16(kernel[c = nt*16+(lane&15)][s][(lane>>4)*8 + t])
__global__ __launch_bounds__(256) void kswz_kernel(const float* __restrict__ kern,
                                                   unsigned short* __restrict__ kswz) {
    int idx  = blockIdx.x * 256 + threadIdx.x;  // 8192
    int lane = idx & 63;
    int nt   = (idx >> 6) & 3;
    int s    = idx >> 8;
    int c    = nt * 16 + (lane & 15);
    int jb   = (lane >> 4) * 8;
    const float* src = kern + c * 1024 + s * 32 + jb;
    union { half8 h; short8 s8; } v;
#pragma unroll
    for (int t = 0; t < 8; ++t) v.h[t] = (_Float16)src[t];  // RNE
    *(short8*)(kswz + (size_t)idx * 8) = v.s8;
}

__device__ __forceinline__ void gld_lds16(const void* g, void* l) {
    __builtin_amdgcn_global_load_lds(
        (const __attribute__((address_space(1))) unsigned int*)g,
        (__attribute__((address_space(3))) unsigned int*)l, 16, 0, 0);
}

__global__ __launch_bounds__(256, 2) void cin_main(const float* __restrict__ x,
                                                   const float* __restrict__ y,
                                                   const unsigned short* __restrict__ kswz,
                                                   float* __restrict__ out_mat,
                                                   float* __restrict__ out_fin) {
    __shared__ unsigned int xs[8 * 1024];                 // 32 KB dup'd f16 x
    __shared__ __align__(16) unsigned short kb[2][8192];  // 2 x 16 KB B chunks

    const int tid  = threadIdx.x;
    const int wave = tid >> 6;        // 0..3
    const int lane = tid & 63;
    const int quad = lane >> 4;
    const int n16  = lane & 15;
    const int b_blk = blockIdx.x * 8;
    const int cq0   = blockIdx.x & 7;

    // ---- DMA first kswz chunk (16 KB: 4 calls x 256 thr x 16 B) ----
#pragma unroll
    for (int r = 0; r < 4; ++r)
        gld_lds16(kswz + (size_t)cq0 * 8192 + (r * 256 + tid) * 8,
                  &kb[0][r * 2048 + wave * 512]);

    // ---- stage x as dup'd f16 pairs: xs[b_loc*1024 + i*32 + d] ----
    {
        const float4* xg4 = (const float4*)(x + (size_t)b_blk * 1024);
#pragma unroll
        for (int r = 0; r < 8; ++r) {
            int i4 = r * 256 + tid;   // 2048 float4 per block
            float4 v = xg4[i4];
            uint4 w;
            w.x = dup_h(v.x); w.y = dup_h(v.y); w.z = dup_h(v.z); w.w = dup_h(v.w);
            *(uint4*)&xs[i4 * 4] = w;
        }
    }

    // ---- y fragments as packed pairs: yv2[mt][p] = {y[b,j=q8+2p,d], y[b,j=q8+2p+1,d]} ----
    const int bpair = wave;  // wave owns b0 = b_blk + wave*2 .. +1
    const int b0 = b_blk + bpair * 2;
    fp16x2 yv2[4][4];
#pragma unroll
    for (int mt = 0; mt < 4; ++mt) {
        const int b = b0 + (mt >> 1);
        const int d = n16 + 16 * (mt & 1);
        const float* yp = y + (size_t)b * 1024 + (quad * 8) * 32 + d;
#pragma unroll
        for (int p = 0; p < 4; ++p)
            yv2[mt][p] = pk2(yp[(2 * p) * 32], yp[(2 * p + 1) * 32]);
    }

    f32x4 acc[4][4];
#pragma unroll
    for (int mt = 0; mt < 4; ++mt)
#pragma unroll
        for (int nt = 0; nt < 4; ++nt) acc[mt][nt] = (f32x4){0.f, 0.f, 0.f, 0.f};

    int xoff[4];
#pragma unroll
    for (int mt = 0; mt < 4; ++mt)
        xoff[mt] = (bpair * 2 + (mt >> 1)) * 1024 + n16 + 16 * (mt & 1);

    __syncthreads();

    for (int p8 = 0; p8 < 8; ++p8) {
        if (p8 < 7) {
            const int cn = (cq0 + p8 + 1) & 7;
            unsigned short* dst = &kb[(p8 + 1) & 1][0];
#pragma unroll
            for (int r = 0; r < 4; ++r)
                gld_lds16(kswz + (size_t)cn * 8192 + (r * 256 + tid) * 8,
                          dst + r * 2048 + wave * 512);
        }

        const unsigned short* kbase = &kb[p8 & 1][0];
        const int sb = ((cq0 + p8) & 7) * 4;
#pragma unroll
        for (int k = 0; k < 4; ++k) {
            half8 bf[4];
#pragma unroll
            for (int nt = 0; nt < 4; ++nt)
                bf[nt] = *(const half8*)(kbase + ((k * 4 + nt) * 64 + lane) * 8);
#pragma unroll
            for (int mt = 0; mt < 4; ++mt) {
                union { unsigned int u; fp16x2 h; } xv;
                xv.u = xs[xoff[mt] + (sb + k) * 32];
                union { half8 h8; fp16x2 h2[4]; } af;
#pragma unroll
                for (int p = 0; p < 4; ++p) af.h2[p] = xv.h * yv2[mt][p];  // v_pk_mul_f16
#pragma unroll
                for (int nt = 0; nt < 4; ++nt)
                    acc[mt][nt] = __builtin_amdgcn_mfma_f32_16x16x32_f16(
                        af.h8, bf[nt], acc[mt][nt], 0, 0, 0);
            }
        }
        __syncthreads();
    }

    // ---- epilogue: output_mat[b][c][d], d = 16*(mt&1) + quad*4 + t ----
#pragma unroll
    for (int mt = 0; mt < 4; ++mt) {
        const int b = b0 + (mt >> 1);
        const int dbase = 16 * (mt & 1) + quad * 4;
#pragma unroll
        for (int nt = 0; nt < 4; ++nt) {
            const int c = nt * 16 + n16;
            *(f32x4*)(out_mat + (size_t)b * 2048 + c * 32 + dbase) = acc[mt][nt];
        }
    }

    // ---- final_output[b][c] = sum_d output_mat[b][c][d] ----
#pragma unroll
    for (int a = 0; a < 2; ++a) {
        const int b = b0 + a;
#pragma unroll
        for (int nt = 0; nt < 4; ++nt) {
            float f = 0.f;
#pragma unroll
            for (int t = 0; t < 4; ++t) f += acc[2 * a][nt][t] + acc[2 * a + 1][nt][t];
            f += __shfl_xor(f, 16);
            f += __shfl_xor(f, 32);
            if (lane < 16) out_fin[(size_t)b * 64 + nt * 16 + n16] = f;
        }
    }
}

extern "C" void kernel_launch(void* const* d_in, const int* in_sizes, int n_in,
                              void* d_out, int out_size, void* d_ws, size_t ws_size,
                              hipStream_t stream) {
    const float* x    = (const float*)d_in[0];   // [4096,32,32]
    const float* y    = (const float*)d_in[1];   // [4096,32,32]
    const float* kern = (const float*)d_in[2];   // [64,32,32]
    float* out_mat = (float*)d_out;                      // [4096,64,32]
    float* out_fin = (float*)d_out + 4096 * 64 * 32;     // [4096,64]
    unsigned short* kswz = (unsigned short*)d_ws;        // 65536 f16 = 128 KB

    kswz_kernel<<<32, 256, 0, stream>>>(kern, kswz);
    cin_main<<<512, 256, 0, stream>>>(x, y, kswz, out_mat, out_fin);
}